// Round 7
// baseline (66.883 us; speedup 1.0000x reference)
//
#include <hip/hip_runtime.h>
#include <hip/hip_bf16.h>
#include <math.h>

#define Nn 1536
#define Bb 2
#define Hh 32
#define Ll 16
#define Nb 96          // Nn/16
#define TREG 4656      // Nb*(Nb+1)/2 regions per batch
#define KSTEPS 48      // 1536/32

typedef short bf16x8 __attribute__((ext_vector_type(8)));
typedef _Float16 f16x8 __attribute__((ext_vector_type(8)));
typedef float f32x4 __attribute__((ext_vector_type(4)));
typedef short short4v __attribute__((ext_vector_type(4)));

__device__ __forceinline__ short f2bf(float x) {
    __hip_bfloat16 h = __float2bfloat16(x);
    return *reinterpret_cast<short*>(&h);
}

// VALU half-swaps (gfx950). Result valid in the LOWER half of each swap domain:
// permswap32: lanes 0-31 receive the value from lane+32 (upper lanes: unchanged).
// permswap16: lanes 0-15 of each 32-group receive lane+16's value.
__device__ __forceinline__ float permswap32(float v) {
    float a = v, b = v;
    asm volatile("v_permlane32_swap_b32 %0, %1" : "+v"(a), "+v"(b));
    return a;
}
__device__ __forceinline__ float permswap16(float v) {
    float a = v, b = v;
    asm volatile("v_permlane16_swap_b32 %0, %1" : "+v"(a), "+v"(b));
    return a;
}

// ---------------- prep: rowsum -> dinv, A -> bf16 with self-loop fill, fused layer-1 xsT ----------------
// one wave per (b,i) row
__global__ void prep_kernel(const float* __restrict__ A,
                            __hip_bfloat16* __restrict__ Abf,
                            float* __restrict__ dinv,
                            const float* __restrict__ emb,
                            const float* __restrict__ W1,
                            __hip_bfloat16* __restrict__ xsT) {
    int w = threadIdx.x >> 6;
    int lane = threadIdx.x & 63;
    int bi = blockIdx.x * 4 + w;
    if (bi >= Bb * Nn) return;
    int b = (bi >= Nn) ? 1 : 0;
    int i = bi - b * Nn;
    const float* Arow = A + (size_t)bi * Nn;
    short* Brow = (short*)Abf + (size_t)bi * Nn;
    float s = 0.f;
#pragma unroll
    for (int it = 0; it < 6; ++it) {
        int j = it * 256 + lane * 4;
        float4 a4 = *reinterpret_cast<const float4*>(Arow + j);
        s += a4.x + a4.y + a4.z + a4.w;
        float e0 = (j + 0 == i) ? ((a4.x == 0.f) ? 1.f : a4.x) : a4.x;
        float e1 = (j + 1 == i) ? ((a4.y == 0.f) ? 1.f : a4.y) : a4.y;
        float e2v = (j + 2 == i) ? ((a4.z == 0.f) ? 1.f : a4.z) : a4.z;
        float e3v = (j + 3 == i) ? ((a4.w == 0.f) ? 1.f : a4.w) : a4.w;
        short4v sv = { f2bf(e0), f2bf(e1), f2bf(e2v), f2bf(e3v) };
        *reinterpret_cast<short4v*>(Brow + j) = sv;
    }
#pragma unroll
    for (int o = 1; o < 64; o <<= 1) s += __shfl_xor(s, o, 64);   // all lanes hold total
    float d = Arow[i];                                            // wave-broadcast load
    float fill = (d == 0.f) ? 1.f : d;
    float deg = s - d + fill;
    float di = (deg > 0.f) ? (1.f / sqrtf(deg)) : 0.f;
    if (lane == 0) dinv[bi] = di;
    if (lane < 32) {                                              // fused layer-1 xsT
        float acc = 0.f;
#pragma unroll
        for (int m = 0; m < 8; ++m)
            acc = fmaf(emb[(size_t)i * 8 + m], W1[m * Hh + lane], acc);
        ((short*)xsT)[(size_t)(b * Hh + lane) * Nn + i] = f2bf(di * acc);
    }
}

// ---------------- GCN propagation via MFMA + fused epilogues ----------------
__global__ __launch_bounds__(256, 1) void prop_kernel(
    const __hip_bfloat16* __restrict__ Abf, const __hip_bfloat16* __restrict__ xsT,
    const float* __restrict__ dinv, const float* __restrict__ bias,
    const float* __restrict__ res, float* __restrict__ out, int has_res,
    const float* __restrict__ Wn, __hip_bfloat16* __restrict__ xsT_next,
    int final_stage,
    const float* __restrict__ Wmu, const float* __restrict__ bmu,
    const float* __restrict__ Wlv, const float* __restrict__ blv,
    const float* __restrict__ E1, const float* __restrict__ e1,
    float* __restrict__ mu, float* __restrict__ lv,
    _Float16* __restrict__ Uh, _Float16* __restrict__ Vh) {
    __shared__ float sRed[4][64][8];
    __shared__ float sOut[16][33];
    __shared__ float sWn[32][32];
    __shared__ float sMu[16][16];
    int t = threadIdx.x, lane = t & 63, w = t >> 6;
    int x = lane & 15, g = lane >> 4;
    int mt = blockIdx.x;
    int b = mt / Nb, it = mt - b * Nb;
    int i0 = it * 16;

    if (Wn) {
        for (int k = t; k < 1024; k += 256) sWn[k >> 5][k & 31] = Wn[k];
    }

    const short* Arow = (const short*)Abf + ((size_t)b * Nn + i0 + x) * Nn + 8 * g;
    const short* X0 = (const short*)xsT + ((size_t)(b * Hh) + x) * Nn + 8 * g;
    const short* X1 = X0 + (size_t)16 * Nn;

    f32x4 acc0 = {0.f, 0.f, 0.f, 0.f};
    f32x4 acc1 = {0.f, 0.f, 0.f, 0.f};
    int ks0 = w * (KSTEPS / 4);
#pragma unroll
    for (int ks = ks0; ks < ks0 + KSTEPS / 4; ++ks) {
        bf16x8 af = *reinterpret_cast<const bf16x8*>(Arow + ks * 32);
        bf16x8 b0 = *reinterpret_cast<const bf16x8*>(X0 + ks * 32);
        bf16x8 b1 = *reinterpret_cast<const bf16x8*>(X1 + ks * 32);
        acc0 = __builtin_amdgcn_mfma_f32_16x16x32_bf16(af, b0, acc0, 0, 0, 0);
        acc1 = __builtin_amdgcn_mfma_f32_16x16x32_bf16(af, b1, acc1, 0, 0, 0);
    }
#pragma unroll
    for (int r = 0; r < 4; ++r) { sRed[w][lane][r] = acc0[r]; sRed[w][lane][4 + r] = acc1[r]; }
    __syncthreads();

    int l = t & 63, xx = l & 15, gg = l >> 4;
#pragma unroll
    for (int q = 0; q < 2; ++q) {
        int ri = (t >> 6) * 2 + q;
        float v = sRed[0][l][ri] + sRed[1][l][ri] + sRed[2][l][ri] + sRed[3][l][ri];
        int row = 4 * gg + (ri & 3);
        int c = (ri < 4) ? xx : (16 + xx);
        int bi = b * Nn + i0 + row;
        v = dinv[bi] * v + bias[c];
        v = fmaxf(v, 0.f);
        if (has_res) v += res[(size_t)bi * Hh + c];
        out[(size_t)bi * Hh + c] = v;
        sOut[row][c] = v;
    }
    __syncthreads();

    if (Wn) {
        for (int k = t; k < 512; k += 256) {
            int r = k >> 5, c = k & 31;
            float acc = 0.f;
#pragma unroll
            for (int m = 0; m < 32; ++m) acc = fmaf(sOut[r][m], sWn[m][c], acc);
            int bi = b * Nn + i0 + r;
            ((short*)xsT_next)[(size_t)(b * Hh + c) * Nn + i0 + r] = f2bf(dinv[bi] * acc);
        }
    }
    if (final_stage) {
        {
            int r = t >> 4, ll = t & 15;
            float am = bmu[ll], av = blv[ll];
#pragma unroll
            for (int m = 0; m < 32; ++m) {
                float hv = sOut[r][m];
                am = fmaf(hv, Wmu[m * Ll + ll], am);
                av = fmaf(hv, Wlv[m * Ll + ll], av);
            }
            size_t o = ((size_t)b * Nn + i0 + r) * Ll + ll;
            mu[o] = am; lv[o] = av;
            sMu[r][ll] = am;
        }
        __syncthreads();
#pragma unroll
        for (int q = 0; q < 4; ++q) {
            int idx = q * 256 + t;
            int r = idx >> 6, c = idx & 63;
            float ua = e1[c], va = 0.f;
#pragma unroll
            for (int m = 0; m < Ll; ++m) {
                float zm = sMu[r][m];
                ua = fmaf(zm, E1[m * 64 + c], ua);
                va = fmaf(zm, E1[(16 + m) * 64 + c], va);
            }
            size_t o = ((size_t)b * Nn + i0 + r) * 64 + c;
            Uh[o] = (_Float16)ua;
            Vh[o] = (_Float16)va;
        }
    }
}

// ---------------- edge MLP: one wave per TWO 16x16 (i,j) regions ----------------
__global__ __launch_bounds__(256) void edge_kernel(
    const _Float16* __restrict__ Uh, const _Float16* __restrict__ Vh,
    const float* __restrict__ E2, const float* __restrict__ e2,
    const float* __restrict__ E3, const float* __restrict__ e3,
    float* __restrict__ adj) {
    __shared__ _Float16 sUp[4][16][4][16];   // 8 KB: [wave][row][k-group][k-halves]
    __shared__ float sW[4][16][20];          // 5.1 KB: result tile (transpose / diag)
    int t = threadIdx.x, lane = t & 63, w = t >> 6;
    int x = lane & 15, g = lane >> 4;

    // ---- per-wave invariants ----
    f16x8 ea[2][2];
#pragma unroll
    for (int ct = 0; ct < 2; ++ct)
#pragma unroll
        for (int ks = 0; ks < 2; ++ks)
#pragma unroll
            for (int jj = 0; jj < 8; ++jj)
                ea[ct][ks][jj] = (_Float16)E2[(32 * ks + 8 * g + jj) * Hh + 16 * ct + x];

    float e2a[4], e2b[4], E3a[4], E3b[4];
#pragma unroll
    for (int rg = 0; rg < 4; ++rg) {
        e2a[rg] = e2[4 * g + rg];      E3a[rg] = E3[4 * g + rg];
        e2b[rg] = e2[16 + 4 * g + rg]; E3b[rg] = E3[16 + 4 * g + rg];
    }
    float e3s = e3[0];

    // ---- first region index for this wave ----
    int wid = blockIdx.x * 4 + w;
    int tr = wid * 2;
    int b = 0;
    if (tr >= TREG) { b = 1; tr -= TREG; }
    float ft = (float)tr;
    int ib = (int)((193.0f - sqrtf(193.0f * 193.0f - 8.0f * ft)) * 0.5f);
    ib = ib < 0 ? 0 : (ib > Nb - 1 ? Nb - 1 : ib);
    while (ib < Nb - 1 && (ib + 1) * Nb - ((ib + 1) * ib) / 2 <= tr) ++ib;
    while (ib > 0 && ib * Nb - (ib * (ib - 1)) / 2 > tr) --ib;
    int jb = ib + (tr - (ib * Nb - (ib * (ib - 1)) / 2));

    const f16x8 fz = {0, 0, 0, 0, 0, 0, 0, 0};
    int ib_prev = -1, b_prev = -1;

#pragma unroll 1
    for (int itr = 0; itr < 2; ++itr) {
        int i0 = ib * 16, j0 = jb * 16;
        bool diag = (ib == jb);

        // V fragments (register-resident): pair col x -> V row j0+x
        const f16x8* Vrow = reinterpret_cast<const f16x8*>(Vh + ((size_t)b * Nn + j0 + x) * 64);
        f16x8 vf0 = Vrow[g];
        f16x8 vf1 = Vrow[4 + g];

        // stage U rows into LDS (skip if same row-panel as previous region)
        if (ib != ib_prev || b != b_prev) {
            int r = lane >> 2, g2 = lane & 3;
            const f16x8* Urow = reinterpret_cast<const f16x8*>(Uh + ((size_t)b * Nn + i0 + r) * 64);
            int sg = (g2 + r) & 3;
            *reinterpret_cast<f16x8*>(&sUp[w][r][sg][0]) = Urow[g2];
            *reinterpret_cast<f16x8*>(&sUp[w][r][sg][8]) = Urow[4 + g2];
            ib_prev = ib; b_prev = b;
        }
        if (diag && lane < 16) sW[w][lane][lane] = 0.f;   // diag zeros

#pragma unroll 4
        for (int r = 0; r < 16; ++r) {
            int sg = (g + r) & 3;
            f16x8 u0 = *reinterpret_cast<const f16x8*>(&sUp[w][r][sg][0]);
            f16x8 u1 = *reinterpret_cast<const f16x8*>(&sUp[w][r][sg][8]);

            // h1 = relu(U[i0+r] + V[j0+x]) packed fp16 (B-fragment: col = pair x)
            f16x8 af0 = __builtin_elementwise_max(u0 + vf0, fz);
            f16x8 af1 = __builtin_elementwise_max(u1 + vf1, fz);

            // h2^T = E2^T @ h1^T, bias folded into C-init; D: row=channel, col=pair
            f32x4 acc0 = {e2a[0], e2a[1], e2a[2], e2a[3]};
            f32x4 acc1 = {e2b[0], e2b[1], e2b[2], e2b[3]};
            acc0 = __builtin_amdgcn_mfma_f32_16x16x32_f16(ea[0][0], af0, acc0, 0, 0, 0);
            acc0 = __builtin_amdgcn_mfma_f32_16x16x32_f16(ea[0][1], af1, acc0, 0, 0, 0);
            acc1 = __builtin_amdgcn_mfma_f32_16x16x32_f16(ea[1][0], af0, acc1, 0, 0, 0);
            acc1 = __builtin_amdgcn_mfma_f32_16x16x32_f16(ea[1][1], af1, acc1, 0, 0, 0);

            // layer 3: lane-local 8-channel partial, then VALU permlane half-swap
            // reduce (valid in lanes 0-15, which are exactly the writers g==0)
            float part = 0.f;
#pragma unroll
            for (int rg = 0; rg < 4; ++rg) {
                part = fmaf(fmaxf(acc0[rg], 0.f), E3a[rg], part);
                part = fmaf(fmaxf(acc1[rg], 0.f), E3b[rg], part);
            }
            part += permswap32(part);   // g0+=g2, g1+=g3 (lanes 0-31 valid)
            part += permswap16(part);   // g0+=g1       (lanes 0-15 valid)

            if (g == 0) {
                float logit = part + e3s;
                float wv = __builtin_amdgcn_rcpf(1.f + __expf(-logit));
                if (!diag) {
                    adj[((size_t)b * Nn + i0 + r) * Nn + j0 + x] = wv;  // coalesced row
                    sW[w][x][r] = wv;                                   // transpose store
                } else if (x > r) {
                    sW[w][r][x] = wv;
                    sW[w][x][r] = wv;
                }
            }
        }

        // region-level coalesced store of the mirrored tile
        {
            int rr = lane >> 2, m4 = (lane & 3) * 4;
            float4 wv4 = *reinterpret_cast<const float4*>(&sW[w][rr][m4]);
            if (!diag)
                *reinterpret_cast<float4*>(&adj[((size_t)b * Nn + j0 + rr) * Nn + i0 + m4]) = wv4;
            else
                *reinterpret_cast<float4*>(&adj[((size_t)b * Nn + i0 + rr) * Nn + i0 + m4]) = wv4;
        }

        // advance to next region (triangular row-major)
        if (++jb == Nb) {
            ++ib; jb = ib;
            if (ib == Nb) { b = 1; ib = 0; jb = 0; }
        }
    }
}

extern "C" void kernel_launch(void* const* d_in, const int* in_sizes, int n_in,
                              void* d_out, int out_size, void* d_ws, size_t ws_size,
                              hipStream_t stream) {
    const float* A   = (const float*)d_in[0];
    const float* emb = (const float*)d_in[1];
    const float* W1  = (const float*)d_in[2];  const float* b1  = (const float*)d_in[3];
    const float* W2  = (const float*)d_in[4];  const float* b2  = (const float*)d_in[5];
    const float* W3  = (const float*)d_in[6];  const float* b3  = (const float*)d_in[7];
    const float* Wmu = (const float*)d_in[8];  const float* bmu = (const float*)d_in[9];
    const float* Wlv = (const float*)d_in[10]; const float* blv = (const float*)d_in[11];
    const float* E1  = (const float*)d_in[12]; const float* e1  = (const float*)d_in[13];
    const float* E2  = (const float*)d_in[14]; const float* e2  = (const float*)d_in[15];
    const float* E3  = (const float*)d_in[16]; const float* e3  = (const float*)d_in[17];

    float* out = (float*)d_out;
    float* ws  = (float*)d_ws;
    float* dinv = ws;
    float* hA   = ws + 3072;
    float* hB   = ws + 101376;
    __hip_bfloat16* xsTa = (__hip_bfloat16*)(ws + 199680);
    __hip_bfloat16* xsTb = (__hip_bfloat16*)(ws + 248832);
    _Float16* Uh = (_Float16*)(ws + 297984);
    _Float16* Vh = (_Float16*)(ws + 396288);
    // Abf aliases the adj region of d_out: written by prep, read by props,
    // overwritten by edge afterwards — stream-ordered, safe.
    __hip_bfloat16* Abf = (__hip_bfloat16*)out;

    float* mu_out = out + (size_t)Bb * Nn * Nn;
    float* lv_out = mu_out + (size_t)Bb * Nn * Ll;

    prep_kernel<<<(Bb * Nn + 3) / 4, 256, 0, stream>>>(A, Abf, dinv, emb, W1, xsTa);

    prop_kernel<<<Bb * Nb, 256, 0, stream>>>(Abf, xsTa, dinv, b1, nullptr, hA, 0,
                                             W2, xsTb, 0,
                                             nullptr, nullptr, nullptr, nullptr,
                                             nullptr, nullptr, nullptr, nullptr,
                                             nullptr, nullptr);
    prop_kernel<<<Bb * Nb, 256, 0, stream>>>(Abf, xsTb, dinv, b2, hA, hB, 1,
                                             W3, xsTa, 0,
                                             nullptr, nullptr, nullptr, nullptr,
                                             nullptr, nullptr, nullptr, nullptr,
                                             nullptr, nullptr);
    prop_kernel<<<Bb * Nb, 256, 0, stream>>>(Abf, xsTa, dinv, b3, hB, hA, 1,
                                             nullptr, nullptr, 1,
                                             Wmu, bmu, Wlv, blv, E1, e1,
                                             mu_out, lv_out, Uh, Vh);

    edge_kernel<<<(2 * TREG) / (4 * 2), 256, 0, stream>>>(Uh, Vh, E2, e2, E3, e3, out);
}